// Round 3
// baseline (250.826 us; speedup 1.0000x reference)
//
#include <hip/hip_runtime.h>
#include <stdint.h>

typedef unsigned short u16;
typedef __bf16 bf16x8 __attribute__((ext_vector_type(8)));
typedef float f32x4 __attribute__((ext_vector_type(4)));
typedef float f32x2 __attribute__((ext_vector_type(2)));

// Sizes
// x:  [16][256][64][64] fp32
// w:  [256][128][4][4]  fp32
// out:[16][128][128][128] fp32
// x_t (ws): [16][66][66][256] bf16, spatially padded by 1 with zeros
// Wk  (ws): [2 p][2 dh][8 kc][2 dw][2 q][128 co][32 ci] bf16
static const size_t XT_BYTES = (size_t)16 * 66 * 66 * 256 * 2; // 35,684,352
static const size_t WK_BYTES = (size_t)2 * 2 * 8 * 2 * 2 * 128 * 32 * 2; // 1,048,576

__device__ __forceinline__ u16 f2bf(float f) {
  unsigned u = __float_as_uint(f);
  unsigned r = (u + 0x7fff + ((u >> 16) & 1)) >> 16; // RNE
  return (u16)r;
}

// async 16B global->LDS
__device__ __forceinline__ void ld_g2l16(const u16* g, void* l) {
  __builtin_amdgcn_global_load_lds(
      (const __attribute__((address_space(1))) unsigned int*)(uintptr_t)g,
      (__attribute__((address_space(3))) unsigned int*)(unsigned int)(uintptr_t)l,
      16, 0, 0);
}

// full-rank 2-bit XOR swizzle
__device__ __forceinline__ int swz4(int row) { return (row ^ (row >> 2)) & 3; }

// ---------------- fused prep: x transpose + weight reorder ----------------
// blocks [0,1056): x fp32 NCHW -> bf16 padded NHWC (one (n,ihp) row each)
// blocks [1056,3104): weights -> [p][dh][kc][dw][q][co][ci32] bf16
// Running both concurrently lets prep_w's scattered gathers fill prep_x's
// latency bubbles, and saves one launch.
__global__ __launch_bounds__(256) void prep_all(const float* __restrict__ x,
                                                const float* __restrict__ w,
                                                u16* __restrict__ xt,
                                                u16* __restrict__ wk) {
  __shared__ __align__(16) u16 sh[64 * 264]; // [iw][ci], pitch 264
  const int t = threadIdx.x;
  const int bx = blockIdx.x;
  if (bx >= 1056) { // ---- prep_w part ----
    int id = (bx - 1056) * 256 + t; // < 524288
    int ci5 = id & 31;
    int co = (id >> 5) & 127;
    int q = (id >> 12) & 1;
    int dw = (id >> 13) & 1;
    int kc = (id >> 14) & 7;
    int dh = (id >> 17) & 1;
    int p = id >> 18;
    int ci = kc * 32 + ci5;
    int kh = 2 * dh + 1 - p;
    int kw = 2 * dw + 1 - q;
    wk[id] = f2bf(w[((ci * 128 + co) * 4 + kh) * 4 + kw]);
    return;
  }
  // ---- prep_x part ----
  const int n = bx / 66;
  const int ihp = bx - n * 66; // 0..65
  u16* xtn = xt + ((size_t)(n * 66 + ihp)) * 66 * 256;
  if (ihp == 0 || ihp == 65) {
    for (int j = 0; j < 9; ++j) {
      int idx = j * 256 + t;
      if (idx < 2112) ((uint4*)xtn)[idx] = make_uint4(0, 0, 0, 0);
    }
    return;
  }
  const int ih = ihp - 1;
  const int iw0 = (t & 15) * 4;
  const int cb = (t >> 4) * 4;  // ci quad base within each 64-group
  const int swz = (t & 3) << 3; // == ((iw>>2)&3)<<3 for this thread's iw range
  const float* xb = x + (size_t)n * 1048576 + (size_t)ih * 64 + iw0;
#pragma unroll
  for (int it = 0; it < 4; ++it) {
    int ci0 = it * 64 + cb;
    float4 v0 = *(const float4*)(xb + (size_t)(ci0 + 0) * 4096);
    float4 v1 = *(const float4*)(xb + (size_t)(ci0 + 1) * 4096);
    float4 v2 = *(const float4*)(xb + (size_t)(ci0 + 2) * 4096);
    float4 v3 = *(const float4*)(xb + (size_t)(ci0 + 3) * 4096);
    int col = ci0 ^ swz;
    ushort4 u;
    u.x = f2bf(v0.x); u.y = f2bf(v1.x); u.z = f2bf(v2.x); u.w = f2bf(v3.x);
    *(ushort4*)&sh[(iw0 + 0) * 264 + col] = u;
    u.x = f2bf(v0.y); u.y = f2bf(v1.y); u.z = f2bf(v2.y); u.w = f2bf(v3.y);
    *(ushort4*)&sh[(iw0 + 1) * 264 + col] = u;
    u.x = f2bf(v0.z); u.y = f2bf(v1.z); u.z = f2bf(v2.z); u.w = f2bf(v3.z);
    *(ushort4*)&sh[(iw0 + 2) * 264 + col] = u;
    u.x = f2bf(v0.w); u.y = f2bf(v1.w); u.z = f2bf(v2.w); u.w = f2bf(v3.w);
    *(ushort4*)&sh[(iw0 + 3) * 264 + col] = u;
  }
  __syncthreads();
#pragma unroll
  for (int j = 0; j < 8; ++j) {
    int idx = j * 256 + t;
    int iw = idx >> 5;    // 0..63
    int chunk = idx & 31; // 0..31
    uint4 v = *(const uint4*)&sh[iw * 264 + ((chunk ^ ((iw >> 2) & 3)) << 3)];
    *(uint4*)&xtn[(size_t)(iw + 1) * 256 + chunk * 8] = v;
  }
  if (t < 64) { // side borders iwp = 0, 65
    int iwp = (t >> 5) * 65;
    int chunk = t & 31;
    *(uint4*)&xtn[(size_t)iwp * 256 + chunk * 8] = make_uint4(0, 0, 0, 0);
  }
}

// ---------------- main: dual-parity implicit GEMM, A-in-registers ---------
// A fragments load straight from global (wk layout makes a wave's fragment
// set one contiguous 1KB block -> perfectly coalesced dwordx4, L2-hot).
// Only B lives in LDS (2x4224 u16, double-buffered). One barrier per pair
// (64 MFMAs), counted vmcnt(4) -- never a full mid-loop drain.
// Quarter-phase A ping-pong: aC/aN sets issued one 16-MFMA phase ahead.
__global__ __launch_bounds__(256, 2) void gemm_ct(const u16* __restrict__ xt,
                                                  const u16* __restrict__ wk,
                                                  const float* __restrict__ bias,
                                                  float* __restrict__ out) {
  __shared__ __align__(16) u16 Bs[2][4224]; // [r][iwp 0..65][32ci], swizzled
  const int t = threadIdx.x;
  const int lane = t & 63;
  const int wv = t >> 6;
  const int wm = wv >> 1, wn = wv & 1; // co-half, m-row
  const int quad = lane >> 4, l15 = lane & 15;

  // bijective XCD swizzle (nwg=1024, %8==0)
  const int id = blockIdx.x;
  const int sid = (id & 7) * 128 + (id >> 3);
  const int mt = sid & 31;
  const int n = (sid >> 5) & 15;
  const int p = sid >> 9;
  const int m0 = mt * 2;

  // per-lane A base: wk[p][s][q][co][ci32] with co = wm*64 + i*16 + l15,
  // chunk quad*8 -> lane addr = l15*64B + quad*16B (1KB contiguous per frag)
  const u16* wka = wk + (size_t)p * 262144 + wm * 2048 + l15 * 32 + quad * 8;
  const u16* xtn = xt + (size_t)n * (66 * 66 * 256);

  // ---- B staging decomposition (source-side swizzle, linear LDS dest) ----
  int bsrc[3];
#pragma unroll
  for (int it = 0; it < 3; ++it) {
    int c = it * 256 + t; // it==2 only active for t<16 (c<528)
    int r = (c >= 264) ? 1 : 0;
    int rem = c - 264 * r;
    int iwp = rem >> 2;
    bsrc[it] = r * 16896 + iwp * 256 + ((rem & 3) ^ swz4(iwp)) * 8;
  }

  // ---- B fragment-read offsets (u16 units), swizzled ----
  int bro[3][4]; // window shifts 0,1,2
#pragma unroll
  for (int k = 0; k < 3; ++k)
#pragma unroll
    for (int j = 0; j < 4; ++j) {
      int b0 = j * 16 + l15 + k;
      bro[k][j] = wn * 2112 + b0 * 32 + (quad ^ swz4(b0)) * 8;
    }

  f32x4 acc[2][4][4];
#pragma unroll
  for (int q = 0; q < 2; ++q)
#pragma unroll
    for (int i = 0; i < 4; ++i)
#pragma unroll
      for (int j = 0; j < 4; ++j) acc[q][i][j] = (f32x4){0.f, 0.f, 0.f, 0.f};

  const int mpp1 = m0 + p + 1;

  auto stageB = [&](int buf, int pr) { // pr = dh*8 + kc
    const int kc = pr & 7, dh = pr >> 3;
    const u16* bbase = xtn + (size_t)(mpp1 - dh) * 16896 + kc * 32;
    u16* Bd = &Bs[buf][0];
    ld_g2l16(bbase + bsrc[0], Bd + t * 8);
    ld_g2l16(bbase + bsrc[1], Bd + (256 + t) * 8);
    if (t < 16) ld_g2l16(bbase + bsrc[2], Bd + (512 + t) * 8);
  };

  bf16x8 aC[4], aN[4];
  auto ldA = [&](bf16x8* a, int s, int q) {
    const u16* b = wka + (size_t)s * 8192 + q * 4096;
#pragma unroll
    for (int i = 0; i < 4; ++i) a[i] = *(const bf16x8*)(b + i * 512);
  };

#define MFMA16(ACC, AF, BF)                                              \
  do {                                                                   \
    _Pragma("unroll") for (int i = 0; i < 4; ++i)                        \
        _Pragma("unroll") for (int j = 0; j < 4; ++j)                    \
        ACC[i][j] = __builtin_amdgcn_mfma_f32_16x16x32_bf16(             \
            AF[i], BF[j], ACC[i][j], 0, 0, 0);                           \
  } while (0)

  // prologue: A(q0,s=0) -> aC, B(pair 0) -> Bs[0]
  ldA(aC, 0, 0);
  stageB(0, 0);
  asm volatile("s_waitcnt vmcnt(0)" ::: "memory");
  __builtin_amdgcn_s_barrier();
  asm volatile("" ::: "memory");

  bf16x8 keep[4]; // shift-1 B fragment, shared by (q0,dw0) and (q1,dw1)
#pragma unroll 1
  for (int pr = 0; pr < 16; ++pr) {
    const u16* Bc = &Bs[pr & 1][0];
    const int s0 = 2 * pr;
    // ---- P0: MFMA(q0,dw0) = aC x keep; issue A(q1,s0) ----
    ldA(aN, s0, 1);
    __builtin_amdgcn_sched_barrier(0);
    bf16x8 b2[4];
#pragma unroll
    for (int j = 0; j < 4; ++j) keep[j] = *(const bf16x8*)(Bc + bro[1][j]);
#pragma unroll
    for (int j = 0; j < 4; ++j) b2[j] = *(const bf16x8*)(Bc + bro[2][j]);
    __builtin_amdgcn_s_setprio(1);
    MFMA16(acc[0], aC, keep);
    __builtin_amdgcn_s_setprio(0);
    __builtin_amdgcn_sched_barrier(0);
    // ---- P1: MFMA(q1,dw0) = aN x b2; issue A(q0,s0+1) + B(pr+1) ----
    ldA(aC, s0 + 1, 0);
    if (pr < 15) stageB((pr + 1) & 1, pr + 1);
    __builtin_amdgcn_sched_barrier(0);
    __builtin_amdgcn_s_setprio(1);
    MFMA16(acc[1], aN, b2);
    __builtin_amdgcn_s_setprio(0);
    __builtin_amdgcn_sched_barrier(0);
    // ---- P2: MFMA(q0,dw1) = aC x b0; issue A(q1,s0+1) ----
    ldA(aN, s0 + 1, 1);
    __builtin_amdgcn_sched_barrier(0);
    bf16x8 b0[4];
#pragma unroll
    for (int j = 0; j < 4; ++j) b0[j] = *(const bf16x8*)(Bc + bro[0][j]);
    __builtin_amdgcn_s_setprio(1);
    MFMA16(acc[0], aC, b0);
    __builtin_amdgcn_s_setprio(0);
    __builtin_amdgcn_sched_barrier(0);
    // ---- P3: MFMA(q1,dw1) = aN x keep; issue A(q0, next pair) ----
    if (pr < 15) ldA(aC, s0 + 2, 0);
    __builtin_amdgcn_sched_barrier(0);
    __builtin_amdgcn_s_setprio(1);
    MFMA16(acc[1], aN, keep);
    __builtin_amdgcn_s_setprio(0);
    // barrier: B(pr+1) must have landed (it's older than the 4 aC loads),
    // aC's 4 loads may stay in flight -> counted, never 0 mid-loop
    if (pr < 15)
      asm volatile("s_waitcnt lgkmcnt(0) vmcnt(4)" ::: "memory");
    else
      asm volatile("s_waitcnt lgkmcnt(0) vmcnt(0)" ::: "memory");
    __builtin_amdgcn_s_barrier();
    asm volatile("" ::: "memory");
  }
#undef MFMA16

  // ---- epilogue: paired-parity nontemporal float2 stores ----
  const int oh = 2 * (m0 + wn) + p;
#pragma unroll
  for (int i = 0; i < 4; ++i) {
#pragma unroll
    for (int j = 0; j < 4; ++j) {
      int l = j * 16 + l15;
#pragma unroll
      for (int r = 0; r < 4; ++r) {
        int co = wm * 64 + i * 16 + quad * 4 + r;
        float bv = bias[co];
        f32x2 v;
        v.x = acc[0][i][j][r] + bv;
        v.y = acc[1][i][j][r] + bv;
        __builtin_nontemporal_store(
            v, (f32x2*)&out[(((size_t)n * 128 + co) * 128 + oh) * 128 + 2 * l]);
      }
    }
  }
}

// ---------------- safety fallback (ws too small): direct fp32 ----------------
__global__ __launch_bounds__(256) void ct_fallback(const float* __restrict__ x,
                                                   const float* __restrict__ w,
                                                   const float* __restrict__ bias,
                                                   float* __restrict__ out) {
  size_t id = (size_t)blockIdx.x * 256 + threadIdx.x;
  if (id >= (size_t)16 * 128 * 128 * 128) return;
  int ow = (int)(id & 127), oh = (int)(id >> 7) & 127;
  int co = (int)(id >> 14) & 127, n = (int)(id >> 21);
  int pp = oh & 1, m = oh >> 1, qq = ow & 1, l = ow >> 1;
  float s = bias[co];
  for (int ci = 0; ci < 256; ++ci) {
    for (int dh = 0; dh < 2; ++dh) {
      int ih = m + pp - dh;
      if (ih < 0 || ih > 63) continue;
      int kh = 2 * dh + 1 - pp;
      for (int dw = 0; dw < 2; ++dw) {
        int iw = l + qq - dw;
        if (iw < 0 || iw > 63) continue;
        int kw = 2 * dw + 1 - qq;
        s += x[(((size_t)n * 256 + ci) * 64 + ih) * 64 + iw] *
             w[((ci * 128 + co) * 4 + kh) * 4 + kw];
      }
    }
  }
  out[id] = s;
}

extern "C" void kernel_launch(void* const* d_in, const int* in_sizes, int n_in,
                              void* d_out, int out_size, void* d_ws, size_t ws_size,
                              hipStream_t stream) {
  const float* x = (const float*)d_in[0];
  const float* w = (const float*)d_in[1];
  const float* bias = (const float*)d_in[2];
  float* out = (float*)d_out;
  if (ws_size >= XT_BYTES + WK_BYTES) {
    u16* xt = (u16*)d_ws;
    u16* wkb = (u16*)((char*)d_ws + XT_BYTES);
    hipLaunchKernelGGL(prep_all, dim3(3104), dim3(256), 0, stream, x, w, xt, wkb);
    hipLaunchKernelGGL(gemm_ct, dim3(1024), dim3(256), 0, stream, xt, wkb, bias, out);
  } else {
    hipLaunchKernelGGL(ct_fallback, dim3(131072), dim3(256), 0, stream, x, w, bias, out);
  }
}

// Round 4
// 241.595 us; speedup vs baseline: 1.0382x; 1.0382x over previous
//
#include <hip/hip_runtime.h>
#include <stdint.h>

typedef unsigned short u16;
typedef __bf16 bf16x8 __attribute__((ext_vector_type(8)));
typedef float f32x4 __attribute__((ext_vector_type(4)));
typedef float f32x2 __attribute__((ext_vector_type(2)));

// Sizes
// x:  [16][256][64][64] fp32
// w:  [256][128][4][4]  fp32
// out:[16][128][128][128] fp32
// x_t (ws): [16][66][66][256] bf16, spatially padded by 1 with zeros
// Wk  (ws): [2 p][2 dh][8 kc][2 dw][2 q][128 co][32 ci] bf16
static const size_t XT_BYTES = (size_t)16 * 66 * 66 * 256 * 2; // 35,684,352
static const size_t WK_BYTES = (size_t)2 * 2 * 8 * 2 * 2 * 128 * 32 * 2; // 1,048,576

__device__ __forceinline__ u16 f2bf(float f) {
  unsigned u = __float_as_uint(f);
  unsigned r = (u + 0x7fff + ((u >> 16) & 1)) >> 16; // RNE
  return (u16)r;
}

// async 16B global->LDS
__device__ __forceinline__ void ld_g2l16(const u16* g, void* l) {
  __builtin_amdgcn_global_load_lds(
      (const __attribute__((address_space(1))) unsigned int*)(uintptr_t)g,
      (__attribute__((address_space(3))) unsigned int*)(unsigned int)(uintptr_t)l,
      16, 0, 0);
}

// full-rank 2-bit XOR swizzle
__device__ __forceinline__ int swz4(int row) { return (row ^ (row >> 2)) & 3; }

// ---------------- fused prep: x transpose + weight reorder ----------------
__global__ __launch_bounds__(256) void prep_all(const float* __restrict__ x,
                                                const float* __restrict__ w,
                                                u16* __restrict__ xt,
                                                u16* __restrict__ wk) {
  __shared__ __align__(16) u16 sh[64 * 264]; // [iw][ci], pitch 264
  const int t = threadIdx.x;
  const int bx = blockIdx.x;
  if (bx >= 1056) { // ---- prep_w part ----
    int id = (bx - 1056) * 256 + t; // < 524288
    int ci5 = id & 31;
    int co = (id >> 5) & 127;
    int q = (id >> 12) & 1;
    int dw = (id >> 13) & 1;
    int kc = (id >> 14) & 7;
    int dh = (id >> 17) & 1;
    int p = id >> 18;
    int ci = kc * 32 + ci5;
    int kh = 2 * dh + 1 - p;
    int kw = 2 * dw + 1 - q;
    wk[id] = f2bf(w[((ci * 128 + co) * 4 + kh) * 4 + kw]);
    return;
  }
  // ---- prep_x part ----
  const int n = bx / 66;
  const int ihp = bx - n * 66; // 0..65
  u16* xtn = xt + ((size_t)(n * 66 + ihp)) * 66 * 256;
  if (ihp == 0 || ihp == 65) {
    for (int j = 0; j < 9; ++j) {
      int idx = j * 256 + t;
      if (idx < 2112) ((uint4*)xtn)[idx] = make_uint4(0, 0, 0, 0);
    }
    return;
  }
  const int ih = ihp - 1;
  const int iw0 = (t & 15) * 4;
  const int cb = (t >> 4) * 4;  // ci quad base within each 64-group
  const int swz = (t & 3) << 3; // == ((iw>>2)&3)<<3 for this thread's iw range
  const float* xb = x + (size_t)n * 1048576 + (size_t)ih * 64 + iw0;
#pragma unroll
  for (int it = 0; it < 4; ++it) {
    int ci0 = it * 64 + cb;
    float4 v0 = *(const float4*)(xb + (size_t)(ci0 + 0) * 4096);
    float4 v1 = *(const float4*)(xb + (size_t)(ci0 + 1) * 4096);
    float4 v2 = *(const float4*)(xb + (size_t)(ci0 + 2) * 4096);
    float4 v3 = *(const float4*)(xb + (size_t)(ci0 + 3) * 4096);
    int col = ci0 ^ swz;
    ushort4 u;
    u.x = f2bf(v0.x); u.y = f2bf(v1.x); u.z = f2bf(v2.x); u.w = f2bf(v3.x);
    *(ushort4*)&sh[(iw0 + 0) * 264 + col] = u;
    u.x = f2bf(v0.y); u.y = f2bf(v1.y); u.z = f2bf(v2.y); u.w = f2bf(v3.y);
    *(ushort4*)&sh[(iw0 + 1) * 264 + col] = u;
    u.x = f2bf(v0.z); u.y = f2bf(v1.z); u.z = f2bf(v2.z); u.w = f2bf(v3.z);
    *(ushort4*)&sh[(iw0 + 2) * 264 + col] = u;
    u.x = f2bf(v0.w); u.y = f2bf(v1.w); u.z = f2bf(v2.w); u.w = f2bf(v3.w);
    *(ushort4*)&sh[(iw0 + 3) * 264 + col] = u;
  }
  __syncthreads();
#pragma unroll
  for (int j = 0; j < 8; ++j) {
    int idx = j * 256 + t;
    int iw = idx >> 5;    // 0..63
    int chunk = idx & 31; // 0..31
    uint4 v = *(const uint4*)&sh[iw * 264 + ((chunk ^ ((iw >> 2) & 3)) << 3)];
    *(uint4*)&xtn[(size_t)(iw + 1) * 256 + chunk * 8] = v;
  }
  if (t < 64) { // side borders iwp = 0, 65
    int iwp = (t >> 5) * 65;
    int chunk = t & 31;
    *(uint4*)&xtn[(size_t)iwp * 256 + chunk * 8] = make_uint4(0, 0, 0, 0);
  }
}

// ---------------- main: 512-thread block, pair-deep LDS pipeline ----------
// Block = (n, p, 4 m-rows); 8 waves: wm = wv>>2 (co-half), wr = wv&3 (m-row).
// Per pair (dh,kc): A = [2dw][2q][128co][32ci] (32 KB), B = [4 rows][66][32]
// (16.5 KB), both double-buffered pair-deep (LDS 97 KB, 1 block/CU, 8 waves).
// Next pair's full stage issued right after the pair-opening barrier ->
// ~620 cyc cover -> end-of-pair vmcnt(0) drain is free. ONE barrier per pair.
__global__ __launch_bounds__(512, 2) void gemm_ct(const u16* __restrict__ xt,
                                                  const u16* __restrict__ wk,
                                                  const float* __restrict__ bias,
                                                  float* __restrict__ out) {
  __shared__ __align__(16) u16 As[2][16384]; // [dw][q][co][ci32], swizzled slots
  __shared__ __align__(16) u16 Bs[2][8448];  // [rr 0..3][iwp 0..65][ci32]
  const int t = threadIdx.x;
  const int lane = t & 63;
  const int wv = t >> 6;
  const int wm = wv >> 2, wr = wv & 3; // co-half, m-row within block
  const int quad = lane >> 4, l15 = lane & 15;

  // bijective XCD swizzle (nwg=512, %8==0)
  const int id = blockIdx.x;
  const int sid = (id & 7) * 64 + (id >> 3);
  const int mt = sid & 15;
  const int n = (sid >> 4) & 15;
  const int p = sid >> 8;
  const int m0 = mt * 4;

  const u16* wkp = wk + (size_t)p * 262144;
  const u16* xtn = xt + (size_t)n * (66 * 66 * 256);

  // ---- staging decomposition (source-side swizzle, linear LDS dest) ----
  int aoffs[4]; // A: 2048 chunks over 512 threads
#pragma unroll
  for (int it = 0; it < 4; ++it) {
    int c = it * 512 + t;
    int rr = c >> 2; // [dw][q][co] row, co = rr & 127
    aoffs[it] = rr * 32 + ((c & 3) ^ swz4(rr & 127)) * 8;
  }
  int bsrc[3]; // B: 1056 chunks; it==2 active only for t<32
#pragma unroll
  for (int it = 0; it < 3; ++it) {
    int c = it * 512 + t;
    int rr = c / 264;
    int rem = c - 264 * rr;
    int iwp = rem >> 2;
    bsrc[it] = rr * 16896 + iwp * 256 + ((rem & 3) ^ swz4(iwp)) * 8;
  }

  // ---- fragment-read offsets (u16 units), swizzled ----
  int aoff[4]; // co-term; phase adds (dw*2+q)*4096
#pragma unroll
  for (int i = 0; i < 4; ++i) {
    int co = wm * 64 + i * 16 + l15;
    aoff[i] = co * 32 + (quad ^ swz4(co)) * 8;
  }
  int bro[3][4]; // window shifts 0,1,2
#pragma unroll
  for (int k = 0; k < 3; ++k)
#pragma unroll
    for (int j = 0; j < 4; ++j) {
      int b0 = j * 16 + l15 + k;
      bro[k][j] = wr * 2112 + b0 * 32 + (quad ^ swz4(b0)) * 8;
    }

  f32x4 acc[2][4][4];
#pragma unroll
  for (int q = 0; q < 2; ++q)
#pragma unroll
    for (int i = 0; i < 4; ++i)
#pragma unroll
      for (int j = 0; j < 4; ++j) acc[q][i][j] = (f32x4){0.f, 0.f, 0.f, 0.f};

  auto stage = [&](int buf, int pr) { // pr = dh*8 + kc
    const int kc = pr & 7, dh = pr >> 3;
    const u16* asrc = wkp + (size_t)(dh * 8 + kc) * 16384;
    u16* Ad = &As[buf][0];
#pragma unroll
    for (int it = 0; it < 4; ++it)
      ld_g2l16(asrc + aoffs[it], Ad + (it * 512 + t) * 8);
    const u16* bbase = xtn + (size_t)(m0 + p - dh + 1) * 16896 + kc * 32;
    u16* Bd = &Bs[buf][0];
    ld_g2l16(bbase + bsrc[0], Bd + t * 8);
    ld_g2l16(bbase + bsrc[1], Bd + (512 + t) * 8);
    if (t < 32) ld_g2l16(bbase + bsrc[2], Bd + (1024 + t) * 8);
  };

#define MFMA16(ACC, AF, BF)                                              \
  do {                                                                   \
    _Pragma("unroll") for (int i = 0; i < 4; ++i)                        \
        _Pragma("unroll") for (int j = 0; j < 4; ++j)                    \
        ACC[i][j] = __builtin_amdgcn_mfma_f32_16x16x32_bf16(             \
            AF[i], BF[j], ACC[i][j], 0, 0, 0);                           \
  } while (0)

  // prologue
  stage(0, 0);
  asm volatile("s_waitcnt vmcnt(0)" ::: "memory");
  __builtin_amdgcn_s_barrier();
  asm volatile("" ::: "memory");

#pragma unroll 2
  for (int pr = 0; pr < 16; ++pr) {
    const u16* Ac = &As[pr & 1][0];
    const u16* Bc = &Bs[pr & 1][0];
    if (pr < 15) stage((pr + 1) & 1, pr + 1); // full next-pair prefetch
    __builtin_amdgcn_sched_barrier(0);
    bf16x8 keep[4], bx[4], af[4];
    // ---- P0: (q0,dw0) = A[0] x shift1 ----
#pragma unroll
    for (int j = 0; j < 4; ++j) keep[j] = *(const bf16x8*)(Bc + bro[1][j]);
#pragma unroll
    for (int i = 0; i < 4; ++i) af[i] = *(const bf16x8*)(Ac + aoff[i]);
    __builtin_amdgcn_s_setprio(1);
    MFMA16(acc[0], af, keep);
    __builtin_amdgcn_s_setprio(0);
    __builtin_amdgcn_sched_barrier(0);
    // ---- P1: (q1,dw0) = A[1] x shift2 ----
#pragma unroll
    for (int j = 0; j < 4; ++j) bx[j] = *(const bf16x8*)(Bc + bro[2][j]);
#pragma unroll
    for (int i = 0; i < 4; ++i) af[i] = *(const bf16x8*)(Ac + 4096 + aoff[i]);
    __builtin_amdgcn_s_setprio(1);
    MFMA16(acc[1], af, bx);
    __builtin_amdgcn_s_setprio(0);
    __builtin_amdgcn_sched_barrier(0);
    // ---- P2: (q0,dw1) = A[2] x shift0 ----
#pragma unroll
    for (int j = 0; j < 4; ++j) bx[j] = *(const bf16x8*)(Bc + bro[0][j]);
#pragma unroll
    for (int i = 0; i < 4; ++i) af[i] = *(const bf16x8*)(Ac + 8192 + aoff[i]);
    __builtin_amdgcn_s_setprio(1);
    MFMA16(acc[0], af, bx);
    __builtin_amdgcn_s_setprio(0);
    __builtin_amdgcn_sched_barrier(0);
    // ---- P3: (q1,dw1) = A[3] x shift1 (keep) ----
#pragma unroll
    for (int i = 0; i < 4; ++i) af[i] = *(const bf16x8*)(Ac + 12288 + aoff[i]);
    __builtin_amdgcn_s_setprio(1);
    MFMA16(acc[1], af, keep);
    __builtin_amdgcn_s_setprio(0);
    // one barrier per pair; next pair's stage had a full pair of cover
    asm volatile("s_waitcnt lgkmcnt(0) vmcnt(0)" ::: "memory");
    __builtin_amdgcn_s_barrier();
    asm volatile("" ::: "memory");
  }
#undef MFMA16

  // ---- epilogue: paired-parity nontemporal float2 stores ----
  const int oh = 2 * (m0 + wr) + p;
#pragma unroll
  for (int i = 0; i < 4; ++i) {
#pragma unroll
    for (int j = 0; j < 4; ++j) {
      int l = j * 16 + l15;
#pragma unroll
      for (int r = 0; r < 4; ++r) {
        int co = wm * 64 + i * 16 + quad * 4 + r;
        float bv = bias[co];
        f32x2 v;
        v.x = acc[0][i][j][r] + bv;
        v.y = acc[1][i][j][r] + bv;
        __builtin_nontemporal_store(
            v, (f32x2*)&out[(((size_t)n * 128 + co) * 128 + oh) * 128 + 2 * l]);
      }
    }
  }
}

// ---------------- safety fallback (ws too small): direct fp32 ----------------
__global__ __launch_bounds__(256) void ct_fallback(const float* __restrict__ x,
                                                   const float* __restrict__ w,
                                                   const float* __restrict__ bias,
                                                   float* __restrict__ out) {
  size_t id = (size_t)blockIdx.x * 256 + threadIdx.x;
  if (id >= (size_t)16 * 128 * 128 * 128) return;
  int ow = (int)(id & 127), oh = (int)(id >> 7) & 127;
  int co = (int)(id >> 14) & 127, n = (int)(id >> 21);
  int pp = oh & 1, m = oh >> 1, qq = ow & 1, l = ow >> 1;
  float s = bias[co];
  for (int ci = 0; ci < 256; ++ci) {
    for (int dh = 0; dh < 2; ++dh) {
      int ih = m + pp - dh;
      if (ih < 0 || ih > 63) continue;
      int kh = 2 * dh + 1 - pp;
      for (int dw = 0; dw < 2; ++dw) {
        int iw = l + qq - dw;
        if (iw < 0 || iw > 63) continue;
        int kw = 2 * dw + 1 - qq;
        s += x[(((size_t)n * 256 + ci) * 64 + ih) * 64 + iw] *
             w[((ci * 128 + co) * 4 + kh) * 4 + kw];
      }
    }
  }
  out[id] = s;
}

extern "C" void kernel_launch(void* const* d_in, const int* in_sizes, int n_in,
                              void* d_out, int out_size, void* d_ws, size_t ws_size,
                              hipStream_t stream) {
  const float* x = (const float*)d_in[0];
  const float* w = (const float*)d_in[1];
  const float* bias = (const float*)d_in[2];
  float* out = (float*)d_out;
  if (ws_size >= XT_BYTES + WK_BYTES) {
    u16* xt = (u16*)d_ws;
    u16* wkb = (u16*)((char*)d_ws + XT_BYTES);
    hipLaunchKernelGGL(prep_all, dim3(3104), dim3(256), 0, stream, x, w, xt, wkb);
    hipLaunchKernelGGL(gemm_ct, dim3(512), dim3(512), 0, stream, xt, wkb, bias, out);
  } else {
    hipLaunchKernelGGL(ct_fallback, dim3(131072), dim3(256), 0, stream, x, w, bias, out);
  }
}